// Round 3
// baseline (1378.882 us; speedup 1.0000x reference)
//
#include <hip/hip_runtime.h>
#include <hip/hip_bf16.h>

#define OBS  128
#define H    64
#define AD   8
#define D1c  4
#define FH   32
#define TRIL 36

#define LOG2PI 1.83787706640934548356f
#define EPSF   1.1920928955078125e-07f

__device__ __forceinline__ float siluf(float v) { return v / (1.f + __expf(-v)); }

__device__ __forceinline__ float waveSum(float v) {
#pragma unroll
  for (int m = 32; m >= 1; m >>= 1) v += __shfl_xor(v, m, 64);
  return v;
}

__global__ __launch_bounds__(256)
void policy_kernel(
    const float* __restrict__ x,    const float* __restrict__ action, const float* __restrict__ z_rpo,
    const float* __restrict__ cW1,  const float* __restrict__ cb1,    const float* __restrict__ c_rms,
    const float* __restrict__ cW2,  const float* __restrict__ cb2,    const float* __restrict__ cW3,
    const float* __restrict__ cb3,
    const float* __restrict__ aW1,  const float* __restrict__ ab1,    const float* __restrict__ aW2,
    const float* __restrict__ ab2,  const float* __restrict__ mW,     const float* __restrict__ mb,
    const float* __restrict__ tW1,  const float* __restrict__ tb1,    const float* __restrict__ t_rms1,
    const float* __restrict__ tW2,  const float* __restrict__ tb2,    const float* __restrict__ t_rms2,
    const float* __restrict__ hW,   const float* __restrict__ hb,
    const float* __restrict__ fW1,  const float* __restrict__ fb1,
    const float* __restrict__ fW2,  const float* __restrict__ fb2,
    float* __restrict__ out, const int Btot)
{
  const int wid  = threadIdx.x >> 6;   // wave within block (0..3)
  const int lane = threadIdx.x & 63;
  const int b    = (blockIdx.x << 2) + wid;   // one element per wave

  __shared__ float xs_s  [4][OBS];
  __shared__ float bufA_s[4][H];
  __shared__ float bufB_s[4][H];
  __shared__ float tri_s [4][TRIL];
  __shared__ float nst_s [4][AD];
  __shared__ float am_s  [4][AD];
  __shared__ float hf_s  [4][FH];
  __shared__ float st_s  [4][AD];

  float* xs   = xs_s[wid];
  float* bufA = bufA_s[wid];
  float* bufB = bufB_s[wid];
  float* tri  = tri_s[wid];
  float* nst  = nst_s[wid];
  float* am   = am_s[wid];
  float* hf   = hf_s[wid];
  float* st   = st_s[wid];

  // ---- load x into LDS ----
  xs[lane]      = x[b * OBS + lane];
  xs[lane + 64] = x[b * OBS + 64 + lane];
  __syncthreads();

  // ================= actor =================
  float acc = ab1[lane];
#pragma unroll 8
  for (int k = 0; k < OBS; ++k) acc = fmaf(xs[k], aW1[k * H + lane], acc);
  bufA[lane] = siluf(acc);
  __syncthreads();

  acc = ab2[lane];
#pragma unroll 8
  for (int k = 0; k < H; ++k) acc = fmaf(bufA[k], aW2[k * H + lane], acc);
  bufB[lane] = siluf(acc);
  __syncthreads();

  if (lane < AD) {
    float m = mb[lane];
#pragma unroll 8
    for (int k = 0; k < H; ++k) m = fmaf(bufB[k], mW[k * AD + lane], m);
    am[lane] = m + z_rpo[b * AD + lane];
  }

  // ================= t branch =================
  acc = tb1[lane];
#pragma unroll 8
  for (int k = 0; k < OBS; ++k) acc = fmaf(xs[k], tW1[k * H + lane], acc);
  float t1 = siluf(acc);
  float ms = waveSum(t1 * t1) * (1.f / 64.f);
  __syncthreads();  // bufA reads (actor L2) done before overwrite
  bufA[lane] = t1 * rsqrtf(ms + EPSF) * t_rms1[lane];
  __syncthreads();

  acc = tb2[lane];
#pragma unroll 8
  for (int k = 0; k < H; ++k) acc = fmaf(bufA[k], tW2[k * H + lane], acc);
  float t2 = siluf(acc);
  ms = waveSum(t2 * t2) * (1.f / 64.f);
  __syncthreads();  // bufB reads (mW head) done before overwrite
  bufB[lane] = t2 * rsqrtf(ms + EPSF) * t_rms2[lane];
  __syncthreads();

  // ---- Cholesky-factor head (lower-tri 8x8, 36 entries) ----
  float ldp = 0.f;
  if (lane < TRIL) {
    float r = hb[lane];
#pragma unroll 8
    for (int k = 0; k < H; ++k) r = fmaf(bufB[k], hW[k * TRIL + lane], r);
    const bool diag = (lane == 0) | (lane == 2) | (lane == 5) | (lane == 9) |
                      (lane == 14) | (lane == 20) | (lane == 27) | (lane == 35);
    float p = r;
    if (diag) {
      p   = fmaxf(r, 0.f) + __logf(1.f + __expf(-fabsf(r)));  // softplus, stable
      ldp = __logf(p);
    }
    tri[lane] = p;
  }
  const float log_det = waveSum(ldp);
  __syncthreads();  // tri visible; bufB reads done

  // ================= critic =================
  acc = cb1[lane];
#pragma unroll 8
  for (int k = 0; k < OBS; ++k) acc = fmaf(xs[k], cW1[k * H + lane], acc);
  float c1 = siluf(acc);
  ms = waveSum(c1 * c1) * (1.f / 64.f);
  bufA[lane] = c1 * rsqrtf(ms + EPSF) * c_rms[lane];
  __syncthreads();

  acc = cb2[lane];
#pragma unroll 8
  for (int k = 0; k < H; ++k) acc = fmaf(bufA[k], cW2[k * H + lane], acc);
  float c2 = siluf(acc);
  const float v = waveSum(c2 * cW3[lane]) + cb3[0];

  // ================= flow =================
  if (lane < AD) nst[lane] = action[b * AD + lane] - am[lane];
  __syncthreads();

  float fld = 0.f;
  for (int i = 3; i >= 0; --i) {
    const float* W1 = fW1 + i * (D1c + OBS) * FH;  // (132,32)
    const float* W2 = fW2 + i * FH * 2 * D1c;      // (32,8)
    const int cb_ = (i & 1) ? 4 : 0;  // cond base: even->x1, odd->x2
    const int yb_ = (i & 1) ? 0 : 4;  // y base

    if (lane < FH) {
      float a2 = fb1[i * FH + lane];
#pragma unroll
      for (int k = 0; k < 4; ++k) a2 = fmaf(nst[cb_ + k], W1[k * FH + lane], a2);
#pragma unroll 8
      for (int k = 0; k < OBS; ++k) a2 = fmaf(xs[k], W1[(4 + k) * FH + lane], a2);
      hf[lane] = siluf(a2);
    }
    __syncthreads();
    if (lane < AD) {
      float a3 = fb2[i * AD + lane];
#pragma unroll 8
      for (int k = 0; k < FH; ++k) a3 = fmaf(hf[k], W2[k * AD + lane], a3);
      st[lane] = a3;
    }
    __syncthreads();
    float sp = 0.f;
    if (lane < 4) {
      const float s  = 2.f * tanhf(st[lane]);
      const float xt = (nst[yb_ + lane] - st[4 + lane]) * __expf(-s);
      nst[yb_ + lane] = xt;
      sp = s;
    }
    fld += waveSum(sp);
    __syncthreads();
  }

  // ================= solve + outputs =================
  if (lane < AD) out[b * AD + lane] = action[b * AD + lane];  // passthrough

  if (lane == 0) {
    float zv[8];
    float mahal = 0.f;
#pragma unroll
    for (int r = 0; r < 8; ++r) {
      float s = nst[r];
      const int base = (r * (r + 1)) >> 1;
      for (int c = 0; c < r; ++c) s -= tri[base + c] * zv[c];
      const float z = s / tri[base + r];
      zv[r] = z;
      mahal += z * z;
    }
    const float lp = -0.5f * (8.f * LOG2PI + mahal) - log_det - fld;
    const float en = 0.5f * (8.f * (1.f + LOG2PI)) + log_det + fld;
    out[(size_t)Btot * 8  + b] = lp;
    out[(size_t)Btot * 9  + b] = en;
    out[(size_t)Btot * 10 + b] = v;
  }
}

extern "C" void kernel_launch(void* const* d_in, const int* in_sizes, int n_in,
                              void* d_out, int out_size, void* d_ws, size_t ws_size,
                              hipStream_t stream) {
  const float* x      = (const float*)d_in[0];
  const float* action = (const float*)d_in[1];
  const float* z_rpo  = (const float*)d_in[2];
  const float* cW1    = (const float*)d_in[3];
  const float* cb1    = (const float*)d_in[4];
  const float* c_rms  = (const float*)d_in[5];
  const float* cW2    = (const float*)d_in[6];
  const float* cb2    = (const float*)d_in[7];
  const float* cW3    = (const float*)d_in[8];
  const float* cb3    = (const float*)d_in[9];
  const float* aW1    = (const float*)d_in[10];
  const float* ab1    = (const float*)d_in[11];
  const float* aW2    = (const float*)d_in[12];
  const float* ab2    = (const float*)d_in[13];
  const float* mW     = (const float*)d_in[14];
  const float* mb     = (const float*)d_in[15];
  const float* tW1    = (const float*)d_in[16];
  const float* tb1    = (const float*)d_in[17];
  const float* t_rms1 = (const float*)d_in[18];
  const float* tW2    = (const float*)d_in[19];
  const float* tb2    = (const float*)d_in[20];
  const float* t_rms2 = (const float*)d_in[21];
  const float* hW     = (const float*)d_in[22];
  const float* hb     = (const float*)d_in[23];
  const float* fW1    = (const float*)d_in[24];
  const float* fb1    = (const float*)d_in[25];
  const float* fW2    = (const float*)d_in[26];
  const float* fb2    = (const float*)d_in[27];
  float* out = (float*)d_out;

  const int Btot = in_sizes[0] / OBS;   // 131072
  dim3 grid(Btot / 4), block(256);
  hipLaunchKernelGGL(policy_kernel, grid, block, 0, stream,
                     x, action, z_rpo, cW1, cb1, c_rms, cW2, cb2, cW3, cb3,
                     aW1, ab1, aW2, ab2, mW, mb, tW1, tb1, t_rms1, tW2, tb2,
                     t_rms2, hW, hb, fW1, fb1, fW2, fb2, out, Btot);
}

// Round 4
// 1257.927 us; speedup vs baseline: 1.0962x; 1.0962x over previous
//
#include <hip/hip_runtime.h>

#define OBS  128
#define Hh   64
#define AD   8
#define FH   32
#define TRIL 36
#define XROW 132   // halfwords per xs row (264B: 8B-aligned rows)
#define BROW 65    // floats per activation row (+1 pad: conflict-free)

#define LOG2PI 1.83787706640934548356f
#define EPSF   1.1920928955078125e-07f

__device__ __forceinline__ float ubits(unsigned u) { union { unsigned u; float f; } c; c.u = u; return c.f; }
__device__ __forceinline__ unsigned fbits(float f) { union { float f; unsigned u; } c; c.f = f; return c.u; }
__device__ __forceinline__ float siluf(float v)    { return v / (1.f + __expf(-v)); }
__device__ __forceinline__ unsigned short f2b(float f) {  // fp32 -> bf16 RTNE
  unsigned u = fbits(f);
  u += 0x7fffu + ((u >> 16) & 1u);
  return (unsigned short)(u >> 16);
}

__global__ __launch_bounds__(64)
void policy_kernel(
    const float* __restrict__ x,    const float* __restrict__ action, const float* __restrict__ z_rpo,
    const float* __restrict__ cW1,  const float* __restrict__ cb1,    const float* __restrict__ c_rms,
    const float* __restrict__ cW2,  const float* __restrict__ cb2,    const float* __restrict__ cW3,
    const float* __restrict__ cb3,
    const float* __restrict__ aW1,  const float* __restrict__ ab1,    const float* __restrict__ aW2,
    const float* __restrict__ ab2,  const float* __restrict__ mW,     const float* __restrict__ mb,
    const float* __restrict__ tW1,  const float* __restrict__ tb1,    const float* __restrict__ t_rms1,
    const float* __restrict__ tW2,  const float* __restrict__ tb2,    const float* __restrict__ t_rms2,
    const float* __restrict__ hW,   const float* __restrict__ hb,
    const float* __restrict__ fW1,  const float* __restrict__ fb1,
    const float* __restrict__ fW2,  const float* __restrict__ fb2,
    float* __restrict__ out, const int Btot)
{
  const int lane = threadIdx.x;        // 0..63 ; lane == batch element
  const int e0   = blockIdx.x << 6;    // first element of this wave
  const int b    = e0 + lane;

  __shared__ unsigned short xs[64 * XROW];  // per-lane x row, bf16
  __shared__ float          buf[64 * BROW]; // per-lane activation row, fp32

  // ---- stage x: coalesced global float4 -> bf16 rows in LDS ----
  {
    const float* xw = x + (size_t)e0 * OBS;
#pragma unroll
    for (int it = 0; it < 32; ++it) {
      const int t = (it << 8) + (lane << 2);        // flat float idx within wave tile
      const float4 v = *(const float4*)(xw + t);
      const int elem = t >> 7;
      const int k    = t & 127;                     // multiple of 4
      uint2 pk;
      pk.x = (unsigned)f2b(v.x) | ((unsigned)f2b(v.y) << 16);
      pk.y = (unsigned)f2b(v.z) | ((unsigned)f2b(v.w) << 16);
      *(uint2*)(xs + elem * XROW + k) = pk;
    }
  }
  __syncthreads();

  const unsigned* xrow = (const unsigned*)(xs + lane * XROW);
  float*          hrow = buf + lane * BROW;

  // =================== actor ===================
  // L1: h1 = silu(x@aW1 + ab1) -> buf
  for (int c = 0; c < 2; ++c) {
    float acc[32];
#pragma unroll
    for (int j = 0; j < 32; ++j) acc[j] = ab1[c * 32 + j];
    const float* W = aW1 + c * 32;
#pragma unroll 2
    for (int kk = 0; kk < 128; kk += 2) {
      const unsigned xv = xrow[kk >> 1];
      const float xa = ubits(xv << 16);
      const float xb = ubits(xv & 0xffff0000u);
      const float* w0 = W + kk * Hh;
#pragma unroll
      for (int j = 0; j < 32; ++j) acc[j] = fmaf(xa, w0[j], acc[j]);
#pragma unroll
      for (int j = 0; j < 32; ++j) acc[j] = fmaf(xb, w0[Hh + j], acc[j]);
    }
#pragma unroll
    for (int j = 0; j < 32; ++j) hrow[c * 32 + j] = siluf(acc[j]);
  }
  // L2 + mean head fused: am = silu(h1@aW2+ab2)@mW + mb
  float am[8];
#pragma unroll
  for (int j = 0; j < 8; ++j) am[j] = mb[j];
  for (int c = 0; c < 2; ++c) {
    float acc[32];
#pragma unroll
    for (int j = 0; j < 32; ++j) acc[j] = ab2[c * 32 + j];
    const float* W = aW2 + c * 32;
#pragma unroll 2
    for (int k = 0; k < Hh; ++k) {
      const float hk = hrow[k];
      const float* w0 = W + k * Hh;
#pragma unroll
      for (int j = 0; j < 32; ++j) acc[j] = fmaf(hk, w0[j], acc[j]);
    }
#pragma unroll
    for (int k = 0; k < 32; ++k) {
      const float h2 = siluf(acc[k]);
      const float* w2 = mW + (c * 32 + k) * AD;
#pragma unroll
      for (int j = 0; j < 8; ++j) am[j] = fmaf(h2, w2[j], am[j]);
    }
  }
  {
    const float4 z0 = *(const float4*)(z_rpo + (size_t)b * AD);
    const float4 z1 = *(const float4*)(z_rpo + (size_t)b * AD + 4);
    am[0] += z0.x; am[1] += z0.y; am[2] += z0.z; am[3] += z0.w;
    am[4] += z1.x; am[5] += z1.y; am[6] += z1.z; am[7] += z1.w;
  }

  // =================== t branch ===================
  float r1;
  {
    float sumsq = 0.f;
    for (int c = 0; c < 2; ++c) {
      float acc[32];
#pragma unroll
      for (int j = 0; j < 32; ++j) acc[j] = tb1[c * 32 + j];
      const float* W = tW1 + c * 32;
#pragma unroll 2
      for (int kk = 0; kk < 128; kk += 2) {
        const unsigned xv = xrow[kk >> 1];
        const float xa = ubits(xv << 16);
        const float xb = ubits(xv & 0xffff0000u);
        const float* w0 = W + kk * Hh;
#pragma unroll
        for (int j = 0; j < 32; ++j) acc[j] = fmaf(xa, w0[j], acc[j]);
#pragma unroll
        for (int j = 0; j < 32; ++j) acc[j] = fmaf(xb, w0[Hh + j], acc[j]);
      }
#pragma unroll
      for (int j = 0; j < 32; ++j) {
        const float s = siluf(acc[j]);
        sumsq += s * s;
        hrow[c * 32 + j] = s * t_rms1[c * 32 + j];   // fold rms weight; scale r1 later
      }
    }
    r1 = rsqrtf(sumsq * (1.f / 64.f) + EPSF);
  }
  // L2 with r1 fold; second rms fold -> st2 regs -> buf
  float r2;
  float st2[64];
  {
    float sumsq2 = 0.f;
    for (int c = 0; c < 2; ++c) {
      float acc[32];
#pragma unroll
      for (int j = 0; j < 32; ++j) acc[j] = 0.f;
      const float* W = tW2 + c * 32;
#pragma unroll 2
      for (int k = 0; k < Hh; ++k) {
        const float hk = hrow[k];
        const float* w0 = W + k * Hh;
#pragma unroll
        for (int j = 0; j < 32; ++j) acc[j] = fmaf(hk, w0[j], acc[j]);
      }
#pragma unroll
      for (int j = 0; j < 32; ++j) {
        const float t2 = siluf(fmaf(r1, acc[j], tb2[c * 32 + j]));
        sumsq2 += t2 * t2;
        st2[c * 32 + j] = t2 * t_rms2[c * 32 + j];
      }
    }
    r2 = rsqrtf(sumsq2 * (1.f / 64.f) + EPSF);
  }
#pragma unroll
  for (int j = 0; j < 64; ++j) hrow[j] = st2[j];
  // Cholesky head: tri = hb + r2 * (st2 @ hW), softplus diag, log-det
  float tri[36];
  float ldet = 0.f;
  {
#pragma unroll
    for (int j = 0; j < 36; ++j) tri[j] = 0.f;
#pragma unroll 2
    for (int k = 0; k < Hh; ++k) {
      const float hk = hrow[k];
      const float* w = hW + k * TRIL;
#pragma unroll
      for (int j = 0; j < 36; ++j) tri[j] = fmaf(hk, w[j], tri[j]);
    }
#pragma unroll
    for (int j = 0; j < 36; ++j) tri[j] = fmaf(r2, tri[j], hb[j]);
#pragma unroll
    for (int d = 0; d < 8; ++d) {
      const int idx = ((d * (d + 1)) >> 1) + d;     // 0,2,5,9,14,20,27,35
      const float r = tri[idx];
      const float p = fmaxf(r, 0.f) + __logf(1.f + __expf(-fabsf(r)));
      tri[idx] = p;
      ldet += __logf(p);
    }
  }

  // =================== critic ===================
  float v;
  {
    float sumsq = 0.f;
    for (int c = 0; c < 2; ++c) {
      float acc[32];
#pragma unroll
      for (int j = 0; j < 32; ++j) acc[j] = cb1[c * 32 + j];
      const float* W = cW1 + c * 32;
#pragma unroll 2
      for (int kk = 0; kk < 128; kk += 2) {
        const unsigned xv = xrow[kk >> 1];
        const float xa = ubits(xv << 16);
        const float xb = ubits(xv & 0xffff0000u);
        const float* w0 = W + kk * Hh;
#pragma unroll
        for (int j = 0; j < 32; ++j) acc[j] = fmaf(xa, w0[j], acc[j]);
#pragma unroll
        for (int j = 0; j < 32; ++j) acc[j] = fmaf(xb, w0[Hh + j], acc[j]);
      }
#pragma unroll
      for (int j = 0; j < 32; ++j) {
        const float s = siluf(acc[j]);
        sumsq += s * s;
        hrow[c * 32 + j] = s * c_rms[c * 32 + j];
      }
    }
    const float rc = rsqrtf(sumsq * (1.f / 64.f) + EPSF);
    float vs = 0.f;
    for (int c = 0; c < 2; ++c) {
      float acc[32];
#pragma unroll
      for (int j = 0; j < 32; ++j) acc[j] = 0.f;
      const float* W = cW2 + c * 32;
#pragma unroll 2
      for (int k = 0; k < Hh; ++k) {
        const float hk = hrow[k];
        const float* w0 = W + k * Hh;
#pragma unroll
        for (int j = 0; j < 32; ++j) acc[j] = fmaf(hk, w0[j], acc[j]);
      }
#pragma unroll
      for (int j = 0; j < 32; ++j) {
        const float cv = siluf(fmaf(rc, acc[j], cb2[c * 32 + j]));
        vs = fmaf(cv, cW3[c * 32 + j], vs);
      }
    }
    v = vs + cb3[0];
  }

  // =================== flow ===================
  float nst[8];
  {
    const float4 a0 = *(const float4*)(action + (size_t)b * AD);
    const float4 a1 = *(const float4*)(action + (size_t)b * AD + 4);
    nst[0] = a0.x - am[0]; nst[1] = a0.y - am[1]; nst[2] = a0.z - am[2]; nst[3] = a0.w - am[3];
    nst[4] = a1.x - am[4]; nst[5] = a1.y - am[5]; nst[6] = a1.z - am[6]; nst[7] = a1.w - am[7];
    *(float4*)(out + (size_t)b * AD)     = a0;   // action passthrough
    *(float4*)(out + (size_t)b * AD + 4) = a1;
  }
  float fld = 0.f;
#pragma unroll
  for (int ii = 0; ii < 4; ++ii) {
    const int i  = 3 - ii;
    const int cb = (i & 1) ? 4 : 0;
    const int yb = (i & 1) ? 0 : 4;
    const float* W1 = fW1 + i * (132 * 32);
    const float* W2 = fW2 + i * (32 * 8);
    float hid[32];
#pragma unroll
    for (int j = 0; j < 32; ++j) hid[j] = fb1[i * 32 + j];
#pragma unroll
    for (int k = 0; k < 4; ++k) {
      const float cv = nst[cb + k];
      const float* w = W1 + k * 32;
#pragma unroll
      for (int j = 0; j < 32; ++j) hid[j] = fmaf(cv, w[j], hid[j]);
    }
    const float* W1x = W1 + 4 * 32;
#pragma unroll 2
    for (int kk = 0; kk < 128; kk += 2) {
      const unsigned xv = xrow[kk >> 1];
      const float xa = ubits(xv << 16);
      const float xb = ubits(xv & 0xffff0000u);
      const float* w0 = W1x + kk * 32;
#pragma unroll
      for (int j = 0; j < 32; ++j) hid[j] = fmaf(xa, w0[j], hid[j]);
#pragma unroll
      for (int j = 0; j < 32; ++j) hid[j] = fmaf(xb, w0[32 + j], hid[j]);
    }
    float st[8];
#pragma unroll
    for (int j = 0; j < 8; ++j) st[j] = fb2[i * 8 + j];
#pragma unroll
    for (int k = 0; k < 32; ++k) {
      const float hv = siluf(hid[k]);
      const float* w = W2 + k * 8;
#pragma unroll
      for (int j = 0; j < 8; ++j) st[j] = fmaf(hv, w[j], st[j]);
    }
#pragma unroll
    for (int j = 0; j < 4; ++j) {
      const float s = 2.f - 4.f / (__expf(2.f * st[j]) + 1.f);   // 2*tanh(st)
      nst[yb + j] = (nst[yb + j] - st[4 + j]) * __expf(-s);
      fld += s;
    }
  }

  // =================== triangular solve + outputs ===================
  {
    float zv[8];
    float mahal = 0.f;
#pragma unroll
    for (int r = 0; r < 8; ++r) {
      float s = nst[r];
      const int base = (r * (r + 1)) >> 1;
#pragma unroll
      for (int cc = 0; cc < r; ++cc) s -= tri[base + cc] * zv[cc];
      const float z = s / tri[base + r];
      zv[r] = z;
      mahal += z * z;
    }
    const float lp = -0.5f * (8.f * LOG2PI + mahal) - ldet - fld;
    const float en = 0.5f * (8.f * (1.f + LOG2PI)) + ldet + fld;
    out[(size_t)Btot * 8  + b] = lp;
    out[(size_t)Btot * 9  + b] = en;
    out[(size_t)Btot * 10 + b] = v;
  }
}

extern "C" void kernel_launch(void* const* d_in, const int* in_sizes, int n_in,
                              void* d_out, int out_size, void* d_ws, size_t ws_size,
                              hipStream_t stream) {
  const float* x      = (const float*)d_in[0];
  const float* action = (const float*)d_in[1];
  const float* z_rpo  = (const float*)d_in[2];
  const float* cW1    = (const float*)d_in[3];
  const float* cb1    = (const float*)d_in[4];
  const float* c_rms  = (const float*)d_in[5];
  const float* cW2    = (const float*)d_in[6];
  const float* cb2    = (const float*)d_in[7];
  const float* cW3    = (const float*)d_in[8];
  const float* cb3    = (const float*)d_in[9];
  const float* aW1    = (const float*)d_in[10];
  const float* ab1    = (const float*)d_in[11];
  const float* aW2    = (const float*)d_in[12];
  const float* ab2    = (const float*)d_in[13];
  const float* mW     = (const float*)d_in[14];
  const float* mb     = (const float*)d_in[15];
  const float* tW1    = (const float*)d_in[16];
  const float* tb1    = (const float*)d_in[17];
  const float* t_rms1 = (const float*)d_in[18];
  const float* tW2    = (const float*)d_in[19];
  const float* tb2    = (const float*)d_in[20];
  const float* t_rms2 = (const float*)d_in[21];
  const float* hW     = (const float*)d_in[22];
  const float* hb     = (const float*)d_in[23];
  const float* fW1    = (const float*)d_in[24];
  const float* fb1    = (const float*)d_in[25];
  const float* fW2    = (const float*)d_in[26];
  const float* fb2    = (const float*)d_in[27];
  float* out = (float*)d_out;

  const int Btot = in_sizes[0] / OBS;   // 131072
  dim3 grid(Btot / 64), block(64);      // one wave per block, lane = element
  hipLaunchKernelGGL(policy_kernel, grid, block, 0, stream,
                     x, action, z_rpo, cW1, cb1, c_rms, cW2, cb2, cW3, cb3,
                     aW1, ab1, aW2, ab2, mW, mb, tW1, tb1, t_rms1, tW2, tb2,
                     t_rms2, hW, hb, fW1, fb1, fW2, fb2, out, Btot);
}

// Round 5
// 811.060 us; speedup vs baseline: 1.7001x; 1.5510x over previous
//
#include <hip/hip_runtime.h>

#define OBS 128
#define LOG2PI 1.83787706640934548356f
#define EPSF   1.1920928955078125e-07f

__device__ __forceinline__ float ubits(unsigned u){union{unsigned u;float f;}c;c.u=u;return c.f;}
__device__ __forceinline__ unsigned fbits(float f){union{float f;unsigned u;}c;c.f=f;return c.u;}
__device__ __forceinline__ float siluf(float v){ return v/(1.f+__expf(-v)); }
__device__ __forceinline__ unsigned packbf(float a,float b){  // RTNE bf16 pair -> dword
  unsigned ua=fbits(a); ua+=0x7fffu+((ua>>16)&1u);
  unsigned ub=fbits(b); ub+=0x7fffu+((ub>>16)&1u);
  return (ua>>16)|(ub&0xffff0000u);
}

// 128-in -> 64-out, x streamed from global (fp32), weights wave-uniform scalar
__device__ __forceinline__ void mvX64(const float* __restrict__ xr,
                                      const float* __restrict__ W,
                                      float acc[64]){
#pragma unroll 2
  for (int i=0;i<32;++i){
    const float4 v=*(const float4*)(xr+4*i);
    const float* w=W+(size_t)(4*i)*64;
#pragma unroll
    for (int j=0;j<64;++j) acc[j]=fmaf(v.x,w[j],acc[j]);
#pragma unroll
    for (int j=0;j<64;++j) acc[j]=fmaf(v.y,w[64+j],acc[j]);
#pragma unroll
    for (int j=0;j<64;++j) acc[j]=fmaf(v.z,w[128+j],acc[j]);
#pragma unroll
    for (int j=0;j<64;++j) acc[j]=fmaf(v.w,w[192+j],acc[j]);
  }
}

// 64-in (packed bf16 LDS row) -> 64-out
__device__ __forceinline__ void mvH64(const unsigned* __restrict__ hrow,
                                      const float* __restrict__ W,
                                      float acc[64]){
#pragma unroll 2
  for (int kk=0;kk<32;++kk){
    const unsigned hv=hrow[kk];
    const float ha=ubits(hv<<16), hb=ubits(hv&0xffff0000u);
    const float* w=W+(size_t)(2*kk)*64;
#pragma unroll
    for (int j=0;j<64;++j) acc[j]=fmaf(ha,w[j],acc[j]);
#pragma unroll
    for (int j=0;j<64;++j) acc[j]=fmaf(hb,w[64+j],acc[j]);
  }
}

// 128-in -> 32-out (flow hidden, x part)
__device__ __forceinline__ void mvX32(const float* __restrict__ xr,
                                      const float* __restrict__ W,
                                      float acc[32]){
#pragma unroll 2
  for (int i=0;i<32;++i){
    const float4 v=*(const float4*)(xr+4*i);
    const float* w=W+(size_t)(4*i)*32;
#pragma unroll
    for (int j=0;j<32;++j) acc[j]=fmaf(v.x,w[j],acc[j]);
#pragma unroll
    for (int j=0;j<32;++j) acc[j]=fmaf(v.y,w[32+j],acc[j]);
#pragma unroll
    for (int j=0;j<32;++j) acc[j]=fmaf(v.z,w[64+j],acc[j]);
#pragma unroll
    for (int j=0;j<32;++j) acc[j]=fmaf(v.w,w[96+j],acc[j]);
  }
}

__global__ __launch_bounds__(64,2)
void policy_kernel(
    const float* __restrict__ x,    const float* __restrict__ action, const float* __restrict__ z_rpo,
    const float* __restrict__ cW1,  const float* __restrict__ cb1,    const float* __restrict__ c_rms,
    const float* __restrict__ cW2,  const float* __restrict__ cb2,    const float* __restrict__ cW3,
    const float* __restrict__ cb3,
    const float* __restrict__ aW1,  const float* __restrict__ ab1,    const float* __restrict__ aW2,
    const float* __restrict__ ab2,  const float* __restrict__ mW,     const float* __restrict__ mb,
    const float* __restrict__ tW1,  const float* __restrict__ tb1,    const float* __restrict__ t_rms1,
    const float* __restrict__ tW2,  const float* __restrict__ tb2,    const float* __restrict__ t_rms2,
    const float* __restrict__ hW,   const float* __restrict__ hb,
    const float* __restrict__ fW1,  const float* __restrict__ fb1,
    const float* __restrict__ fW2,  const float* __restrict__ fb2,
    float* __restrict__ out, const int Btot)
{
  const int lane = threadIdx.x;            // lane == element within wave
  const int b    = (blockIdx.x << 6) + lane;
  __shared__ unsigned hbuf[64*33];         // per-lane packed-bf16 activation row
  unsigned* hrow = hbuf + lane*33;         // stride 33 dwords: conflict-free
  const float* xr = x + (size_t)b*OBS;

  float acc[64];

  // =================== critic ===================
#pragma unroll
  for (int j=0;j<64;++j) acc[j]=cb1[j];
  mvX64(xr, cW1, acc);
  float v;
  {
    float sumsq=0.f;
#pragma unroll
    for (int j=0;j<64;j+=2){
      const float s0=siluf(acc[j]), s1=siluf(acc[j+1]);
      sumsq += s0*s0 + s1*s1;
      hrow[j>>1]=packbf(s0*c_rms[j], s1*c_rms[j+1]);
    }
    const float rc=rsqrtf(sumsq*(1.f/64.f)+EPSF);
#pragma unroll
    for (int j=0;j<64;++j) acc[j]=0.f;
    mvH64(hrow, cW2, acc);
    float vs=0.f;
#pragma unroll
    for (int j=0;j<64;++j) vs=fmaf(siluf(fmaf(rc,acc[j],cb2[j])), cW3[j], vs);
    v = vs + cb3[0];
  }

  // =================== actor ===================
#pragma unroll
  for (int j=0;j<64;++j) acc[j]=ab1[j];
  mvX64(xr, aW1, acc);
#pragma unroll
  for (int j=0;j<64;j+=2) hrow[j>>1]=packbf(siluf(acc[j]), siluf(acc[j+1]));
#pragma unroll
  for (int j=0;j<64;++j) acc[j]=ab2[j];
  mvH64(hrow, aW2, acc);
  float am[8];
#pragma unroll
  for (int p=0;p<8;++p) am[p]=mb[p];
#pragma unroll
  for (int j=0;j<64;++j){
    const float h2=siluf(acc[j]);
    const float* w2=mW+(size_t)j*8;
#pragma unroll
    for (int p=0;p<8;++p) am[p]=fmaf(h2,w2[p],am[p]);
  }
  {
    const float4 z0=*(const float4*)(z_rpo+(size_t)b*8);
    const float4 z1=*(const float4*)(z_rpo+(size_t)b*8+4);
    am[0]+=z0.x; am[1]+=z0.y; am[2]+=z0.z; am[3]+=z0.w;
    am[4]+=z1.x; am[5]+=z1.y; am[6]+=z1.z; am[7]+=z1.w;
  }

  // =================== t branch ===================
#pragma unroll
  for (int j=0;j<64;++j) acc[j]=tb1[j];
  mvX64(xr, tW1, acc);
  float r1;
  {
    float sumsq=0.f;
#pragma unroll
    for (int j=0;j<64;j+=2){
      const float s0=siluf(acc[j]), s1=siluf(acc[j+1]);
      sumsq += s0*s0 + s1*s1;
      hrow[j>>1]=packbf(s0*t_rms1[j], s1*t_rms1[j+1]);
    }
    r1=rsqrtf(sumsq*(1.f/64.f)+EPSF);
  }
#pragma unroll
  for (int j=0;j<64;++j) acc[j]=0.f;
  mvH64(hrow, tW2, acc);
  // epilogue: t2 = silu(r1*acc + tb2); s = t2*t_rms2; sumsq2; pack s -> hrow
  float r2;
  {
    float sumsq2=0.f;
#pragma unroll
    for (int j=0;j<64;j+=2){
      const float t20=siluf(fmaf(r1,acc[j],  tb2[j]));
      const float t21=siluf(fmaf(r1,acc[j+1],tb2[j+1]));
      sumsq2 += t20*t20 + t21*t21;
      hrow[j>>1]=packbf(t20*t_rms2[j], t21*t_rms2[j+1]);
    }
    r2=rsqrtf(sumsq2*(1.f/64.f)+EPSF);
  }
  // Cholesky head: tri_raw = s @ hW (rolled over LDS row), then tri = hb + r2*tri_raw
  float tri[36];
#pragma unroll
  for (int j=0;j<36;++j) tri[j]=0.f;
#pragma unroll 2
  for (int kk=0;kk<32;++kk){
    const unsigned hv=hrow[kk];
    const float sa=ubits(hv<<16), sb=ubits(hv&0xffff0000u);
    const float* w=hW+(size_t)(2*kk)*36;
#pragma unroll
    for (int j=0;j<36;++j) tri[j]=fmaf(sa,w[j],tri[j]);
#pragma unroll
    for (int j=0;j<36;++j) tri[j]=fmaf(sb,w[36+j],tri[j]);
  }
  float ldet=0.f;
#pragma unroll
  for (int j=0;j<36;++j) tri[j]=fmaf(r2,tri[j],hb[j]);
#pragma unroll
  for (int d=0;d<8;++d){
    const int idx=((d*(d+1))>>1)+d;
    const float r=tri[idx];
    const float p=fmaxf(r,0.f)+__logf(1.f+__expf(-fabsf(r)));  // stable softplus
    tri[idx]=p;
    ldet+=__logf(p);
  }

  // =================== flow ===================
  float nst[8];
  {
    const float4 a0=*(const float4*)(action+(size_t)b*8);
    const float4 a1=*(const float4*)(action+(size_t)b*8+4);
    nst[0]=a0.x-am[0]; nst[1]=a0.y-am[1]; nst[2]=a0.z-am[2]; nst[3]=a0.w-am[3];
    nst[4]=a1.x-am[4]; nst[5]=a1.y-am[5]; nst[6]=a1.z-am[6]; nst[7]=a1.w-am[7];
    *(float4*)(out+(size_t)b*8)=a0;        // action passthrough
    *(float4*)(out+(size_t)b*8+4)=a1;
  }
  float fld=0.f;
#pragma unroll
  for (int ii=0;ii<4;++ii){
    const int i=3-ii;
    const int cbase=(i&1)?4:0, ybase=(i&1)?0:4;
    const float* W1=fW1+(size_t)i*(132*32);
    const float* W2=fW2+(size_t)i*(32*8);
    float hid[32];
#pragma unroll
    for (int j=0;j<32;++j) hid[j]=fb1[i*32+j];
#pragma unroll
    for (int k=0;k<4;++k){
      const float cv=nst[cbase+k];
      const float* w=W1+(size_t)k*32;
#pragma unroll
      for (int j=0;j<32;++j) hid[j]=fmaf(cv,w[j],hid[j]);
    }
    mvX32(xr, W1+4*32, hid);
    float st[8];
#pragma unroll
    for (int j=0;j<8;++j) st[j]=fb2[i*8+j];
#pragma unroll
    for (int k=0;k<32;++k){
      const float hv=siluf(hid[k]);
      const float* w=W2+(size_t)k*8;
#pragma unroll
      for (int j=0;j<8;++j) st[j]=fmaf(hv,w[j],st[j]);
    }
#pragma unroll
    for (int j=0;j<4;++j){
      const float s=2.f-4.f/(__expf(2.f*st[j])+1.f);       // 2*tanh(st)
      nst[ybase+j]=(nst[ybase+j]-st[4+j])*__expf(-s);
      fld+=s;
    }
  }

  // =================== triangular solve + outputs ===================
  {
    float zv[8];
    float mahal=0.f;
#pragma unroll
    for (int r=0;r<8;++r){
      float s=nst[r];
      const int base=(r*(r+1))>>1;
#pragma unroll
      for (int cc=0;cc<r;++cc) s-=tri[base+cc]*zv[cc];
      const float z=s/tri[base+r];
      zv[r]=z;
      mahal+=z*z;
    }
    const float lp=-0.5f*(8.f*LOG2PI+mahal)-ldet-fld;
    const float en= 0.5f*(8.f*(1.f+LOG2PI))+ldet+fld;
    out[(size_t)Btot*8 +b]=lp;
    out[(size_t)Btot*9 +b]=en;
    out[(size_t)Btot*10+b]=v;
  }
}

extern "C" void kernel_launch(void* const* d_in, const int* in_sizes, int n_in,
                              void* d_out, int out_size, void* d_ws, size_t ws_size,
                              hipStream_t stream) {
  const float* x      = (const float*)d_in[0];
  const float* action = (const float*)d_in[1];
  const float* z_rpo  = (const float*)d_in[2];
  const float* cW1    = (const float*)d_in[3];
  const float* cb1    = (const float*)d_in[4];
  const float* c_rms  = (const float*)d_in[5];
  const float* cW2    = (const float*)d_in[6];
  const float* cb2    = (const float*)d_in[7];
  const float* cW3    = (const float*)d_in[8];
  const float* cb3    = (const float*)d_in[9];
  const float* aW1    = (const float*)d_in[10];
  const float* ab1    = (const float*)d_in[11];
  const float* aW2    = (const float*)d_in[12];
  const float* ab2    = (const float*)d_in[13];
  const float* mW     = (const float*)d_in[14];
  const float* mb     = (const float*)d_in[15];
  const float* tW1    = (const float*)d_in[16];
  const float* tb1    = (const float*)d_in[17];
  const float* t_rms1 = (const float*)d_in[18];
  const float* tW2    = (const float*)d_in[19];
  const float* tb2    = (const float*)d_in[20];
  const float* t_rms2 = (const float*)d_in[21];
  const float* hW     = (const float*)d_in[22];
  const float* hb     = (const float*)d_in[23];
  const float* fW1    = (const float*)d_in[24];
  const float* fb1    = (const float*)d_in[25];
  const float* fW2    = (const float*)d_in[26];
  const float* fb2    = (const float*)d_in[27];
  float* out = (float*)d_out;

  const int Btot = in_sizes[0] / OBS;   // 131072
  dim3 grid(Btot/64), block(64);        // one wave per block, lane = element
  hipLaunchKernelGGL(policy_kernel, grid, block, 0, stream,
                     x, action, z_rpo, cW1, cb1, c_rms, cW2, cb2, cW3, cb3,
                     aW1, ab1, aW2, ab2, mW, mb, tW1, tb1, t_rms1, tW2, tb2,
                     t_rms2, hW, hb, fW1, fb1, fW2, fb2, out, Btot);
}

// Round 6
// 213.533 us; speedup vs baseline: 6.4575x; 3.7983x over previous
//
#include <hip/hip_runtime.h>

typedef __attribute__((ext_vector_type(8))) short    v8s;   // 8 bf16 (4 VGPR)
typedef __attribute__((ext_vector_type(4))) float    f4;
typedef __attribute__((ext_vector_type(2))) float    f2;
typedef __attribute__((ext_vector_type(2))) unsigned u32x2;

#define MFMA16 __builtin_amdgcn_mfma_f32_16x16x32_bf16

// ---- d_ws layout ----
// bf16 section (ushort units)
#define AW1T 0        // [64][128]
#define TW1T 8192
#define CW1T 16384
#define AW2T 24576    // [64][64]
#define TW2T 28672
#define CW2T 32768
#define MWT  36864    // [16][64] rows 8..15 zero
#define HWT  37888    // [48][64] rows diag-first-permuted, 36..47 zero
#define FW1XT 40960   // + i*4096 : [32][128]
#define FW2T  57344   // + i*512  : [16][32] rows 8..15 zero
#define WS_BF16_TOTAL 59392
// f32 section (float units, base = d_ws + WS_BF16_TOTAL*2)
#define W1CTO 0       // + i*128 : [32][4]  (cond weights, row=neuron, k=0..3)
#define HBPO  512     // [48] hb permuted

#define LOG2PI 1.83787706640934548356f
#define EPSF   1.1920928955078125e-07f

__device__ __constant__ int PERM[36] = {0,2,5,9,14,20,27,35,
  1,3,4,6,7,8,10,11,12,13,15,16,17,18,19,21,22,23,24,25,26,28,29,30,31,32,33,34};

__device__ __forceinline__ float ubits(unsigned u){union{unsigned u;float f;}c;c.u=u;return c.f;}
__device__ __forceinline__ unsigned fbits(float f){union{float f;unsigned u;}c;c.f=f;return c.u;}
__device__ __forceinline__ float siluf(float v){ return v/(1.f+__expf(-v)); }
__device__ __forceinline__ unsigned pk2(float a,float b){            // 2x f32 -> packed bf16 (RTNE)
  unsigned ua=fbits(a); ua+=0x7fffu+((ua>>16)&1u);
  unsigned ub=fbits(b); ub+=0x7fffu+((ub>>16)&1u);
  return (ua>>16)|(ub&0xffff0000u);
}
__device__ __forceinline__ unsigned short f2bu(float a){
  unsigned ua=fbits(a); ua+=0x7fffu+((ua>>16)&1u);
  return (unsigned short)(ua>>16);
}
__device__ __forceinline__ float qsum(float v){                       // sum over the 4 quads
  v += __shfl_xor(v,16,64); v += __shfl_xor(v,32,64); return v;
}

// ============ prep: transpose/pad/permute weights into ws (bf16) ============
__global__ __launch_bounds__(256)
void prep_kernel(const float* __restrict__ aW1, const float* __restrict__ aW2,
                 const float* __restrict__ mW,  const float* __restrict__ tW1,
                 const float* __restrict__ tW2, const float* __restrict__ hW,
                 const float* __restrict__ hb,  const float* __restrict__ cW1,
                 const float* __restrict__ cW2, const float* __restrict__ fW1,
                 const float* __restrict__ fW2,
                 unsigned short* __restrict__ ws16, float* __restrict__ wsf)
{
  const int tid = blockIdx.x*256 + threadIdx.x;
  const int stride = gridDim.x*256;
  for (int idx=tid; idx<64*128; idx+=stride){        // [n][k] <- [k][n]
    int n=idx>>7, k=idx&127;
    ws16[AW1T+idx]=f2bu(aW1[k*64+n]);
    ws16[TW1T+idx]=f2bu(tW1[k*64+n]);
    ws16[CW1T+idx]=f2bu(cW1[k*64+n]);
  }
  for (int idx=tid; idx<64*64; idx+=stride){
    int n=idx>>6, k=idx&63;
    ws16[AW2T+idx]=f2bu(aW2[k*64+n]);
    ws16[TW2T+idx]=f2bu(tW2[k*64+n]);
    ws16[CW2T+idx]=f2bu(cW2[k*64+n]);
  }
  for (int idx=tid; idx<16*64; idx+=stride){
    int n=idx>>6, k=idx&63;
    ws16[MWT+idx]=f2bu(n<8 ? mW[k*8+n] : 0.f);
  }
  for (int idx=tid; idx<48*64; idx+=stride){         // diag-first row permutation
    int n=idx>>6, k=idx&63;
    ws16[HWT+idx]=f2bu(n<36 ? hW[k*36+PERM[n]] : 0.f);
  }
  for (int idx=tid; idx<4*32*128; idx+=stride){      // fW1 x-part
    int i=idx>>12, rem=idx&4095, n=rem>>7, k=rem&127;
    ws16[FW1XT+idx]=f2bu(fW1[i*4224 + (4+k)*32 + n]);
  }
  for (int idx=tid; idx<4*16*32; idx+=stride){
    int i=idx>>9, rem=idx&511, n=rem>>5, k=rem&31;
    ws16[FW2T+idx]=f2bu(n<8 ? fW2[i*256 + k*8 + n] : 0.f);
  }
  for (int idx=tid; idx<4*32*4; idx+=stride){        // fW1 cond part, fp32 [n][k]
    int i=idx>>7, rem=idx&127, n=rem>>2, k=rem&3;
    wsf[W1CTO+idx]=fW1[i*4224 + k*32 + n];
  }
  for (int idx=tid; idx<48; idx+=stride)
    wsf[HBPO+idx] = idx<36 ? hb[PERM[idx]] : 0.f;
}

// ============ GEMM helpers (all outputs transposed: rows=neurons, cols=elems) ===
template<int NWT>
__device__ __forceinline__ void gemmX(const unsigned short* __restrict__ Wt,
                                      const v8s* __restrict__ xf,
                                      f4 (*acc)[4], int c, int q)
{
#pragma unroll
  for (int kt=0; kt<4; ++kt){
    v8s wf[NWT];
#pragma unroll
    for (int wt=0; wt<NWT; ++wt)
      wf[wt] = *(const v8s*)(Wt + (wt*16 + c)*128 + kt*32 + q*8);
#pragma unroll
    for (int wt=0; wt<NWT; ++wt)
#pragma unroll
      for (int et=0; et<4; ++et)
        acc[wt][et] = MFMA16(wf[wt], xf[et*4+kt], acc[wt][et], 0,0,0);
  }
}

template<int NWT>
__device__ __forceinline__ void gemmH(const unsigned short* __restrict__ Wt,
                                      const unsigned short* __restrict__ actL,
                                      f4 (*acc)[4], int c, int q)
{
#pragma unroll
  for (int kt=0; kt<2; ++kt){
    v8s wf[NWT];
#pragma unroll
    for (int wt=0; wt<NWT; ++wt)
      wf[wt] = *(const v8s*)(Wt + (wt*16 + c)*64 + kt*32 + q*8);
    v8s af[4];
#pragma unroll
    for (int et=0; et<4; ++et)
      af[et] = *(const v8s*)(actL + (et*16+c)*72 + kt*32 + q*8);
#pragma unroll
    for (int wt=0; wt<NWT; ++wt)
#pragma unroll
      for (int et=0; et<4; ++et)
        acc[wt][et] = MFMA16(wf[wt], af[et], acc[wt][et], 0,0,0);
  }
}

// ============ main ============
__global__ __launch_bounds__(64,2)
void policy_kernel(
    const float* __restrict__ x,    const float* __restrict__ action, const float* __restrict__ z_rpo,
    const float* __restrict__ cb1,  const float* __restrict__ c_rms,  const float* __restrict__ cb2,
    const float* __restrict__ cW3,  const float* __restrict__ cb3,
    const float* __restrict__ ab1,  const float* __restrict__ ab2,    const float* __restrict__ mb,
    const float* __restrict__ tb1,  const float* __restrict__ t_rms1, const float* __restrict__ tb2,
    const float* __restrict__ t_rms2,
    const float* __restrict__ fb1,  const float* __restrict__ fb2,
    const unsigned short* __restrict__ ws16, const float* __restrict__ wsf,
    float* __restrict__ out, const int Btot)
{
  const int lane = threadIdx.x;
  const int q = lane >> 4, c = lane & 15;
  const int b0 = blockIdx.x << 6;

  __shared__ alignas(16) unsigned char smem[19968];
  unsigned short* actL = (unsigned short*)smem;            // [64][72] bf16 (flow: hidL [64][40])
  unsigned short* hidL = (unsigned short*)smem;
  unsigned short* triL = (unsigned short*)(smem + 9216);   // [64][44] bf16
  float*          nstL = (float*)(smem + 14848);           // [64][10]
  float*          amL  = (float*)(smem + 17408);           // [64][10] (st aliases)

  // ---- resident x A/B-fragments: xf[et*4+kt], value x[et*16+c][kt*32+q*8 ..+8] ----
  v8s xf[16];
  {
    const float* xb = x + (size_t)b0*128;
#pragma unroll
    for (int et=0; et<4; ++et)
#pragma unroll
      for (int kt=0; kt<4; ++kt){
        const float* p = xb + (size_t)(et*16+c)*128 + kt*32 + q*8;
        f4 u0 = *(const f4*)p, u1 = *(const f4*)(p+4);
        union { unsigned u[4]; v8s v; } r;
        r.u[0]=pk2(u0[0],u0[1]); r.u[1]=pk2(u0[2],u0[3]);
        r.u[2]=pk2(u1[0],u1[1]); r.u[3]=pk2(u1[2],u1[3]);
        xf[et*4+kt] = r.v;
      }
  }

  f4 acc[4][4];
  const f4 z4 = {0.f,0.f,0.f,0.f};

  // =================== actor ===================
#pragma unroll
  for (int wt=0; wt<4; ++wt) for (int et=0; et<4; ++et) acc[wt][et]=z4;
  gemmX<4>(ws16+AW1T, xf, acc, c, q);
#pragma unroll
  for (int wt=0; wt<4; ++wt){
    const f4 bv = *(const f4*)(ab1 + wt*16 + q*4);
#pragma unroll
    for (int et=0; et<4; ++et){
      float s0=siluf(acc[wt][et][0]+bv[0]), s1=siluf(acc[wt][et][1]+bv[1]);
      float s2=siluf(acc[wt][et][2]+bv[2]), s3=siluf(acc[wt][et][3]+bv[3]);
      u32x2 u = {pk2(s0,s1), pk2(s2,s3)};
      *(u32x2*)(actL + (et*16+c)*72 + wt*16 + q*4) = u;
    }
  }
#pragma unroll
  for (int wt=0; wt<4; ++wt) for (int et=0; et<4; ++et) acc[wt][et]=z4;
  gemmH<4>(ws16+AW2T, actL, acc, c, q);
#pragma unroll
  for (int wt=0; wt<4; ++wt){
    const f4 bv = *(const f4*)(ab2 + wt*16 + q*4);
#pragma unroll
    for (int et=0; et<4; ++et){
      float s0=siluf(acc[wt][et][0]+bv[0]), s1=siluf(acc[wt][et][1]+bv[1]);
      float s2=siluf(acc[wt][et][2]+bv[2]), s3=siluf(acc[wt][et][3]+bv[3]);
      u32x2 u = {pk2(s0,s1), pk2(s2,s3)};
      *(u32x2*)(actL + (et*16+c)*72 + wt*16 + q*4) = u;
    }
  }
  {
    f4 am1[1][4]; am1[0][0]=z4; am1[0][1]=z4; am1[0][2]=z4; am1[0][3]=z4;
    gemmH<1>(ws16+MWT, actL, am1, c, q);
    if (q<2){
      const f4 mbv = *(const f4*)(mb + q*4);
#pragma unroll
      for (int et=0; et<4; ++et){
        float* p = amL + (et*16+c)*10 + q*4;
        *(f2*)p     = (f2){am1[0][et][0]+mbv[0], am1[0][et][1]+mbv[1]};
        *(f2*)(p+2) = (f2){am1[0][et][2]+mbv[2], am1[0][et][3]+mbv[3]};
      }
    }
  }

  // =================== t branch ===================
#pragma unroll
  for (int wt=0; wt<4; ++wt) for (int et=0; et<4; ++et) acc[wt][et]=z4;
  gemmX<4>(ws16+TW1T, xf, acc, c, q);
  float r1[4];
  {
    float ss[4]={0.f,0.f,0.f,0.f};
#pragma unroll
    for (int wt=0; wt<4; ++wt){
      const f4 bv = *(const f4*)(tb1 + wt*16 + q*4);
      const f4 rw = *(const f4*)(t_rms1 + wt*16 + q*4);
#pragma unroll
      for (int et=0; et<4; ++et){
        float s0=siluf(acc[wt][et][0]+bv[0]), s1=siluf(acc[wt][et][1]+bv[1]);
        float s2=siluf(acc[wt][et][2]+bv[2]), s3=siluf(acc[wt][et][3]+bv[3]);
        ss[et] += s0*s0+s1*s1+s2*s2+s3*s3;
        u32x2 u = {pk2(s0*rw[0],s1*rw[1]), pk2(s2*rw[2],s3*rw[3])};
        *(u32x2*)(actL + (et*16+c)*72 + wt*16 + q*4) = u;
      }
    }
#pragma unroll
    for (int et=0; et<4; ++et) r1[et]=rsqrtf(qsum(ss[et])*(1.f/64.f)+EPSF);
  }
#pragma unroll
  for (int wt=0; wt<4; ++wt) for (int et=0; et<4; ++et) acc[wt][et]=z4;
  gemmH<4>(ws16+TW2T, actL, acc, c, q);
  float r2[4];
  {
    float ss[4]={0.f,0.f,0.f,0.f};
#pragma unroll
    for (int wt=0; wt<4; ++wt){
      const f4 bv = *(const f4*)(tb2 + wt*16 + q*4);
      const f4 rw = *(const f4*)(t_rms2 + wt*16 + q*4);
#pragma unroll
      for (int et=0; et<4; ++et){
        float s0=siluf(r1[et]*acc[wt][et][0]+bv[0]), s1=siluf(r1[et]*acc[wt][et][1]+bv[1]);
        float s2=siluf(r1[et]*acc[wt][et][2]+bv[2]), s3=siluf(r1[et]*acc[wt][et][3]+bv[3]);
        ss[et] += s0*s0+s1*s1+s2*s2+s3*s3;
        u32x2 u = {pk2(s0*rw[0],s1*rw[1]), pk2(s2*rw[2],s3*rw[3])};
        *(u32x2*)(actL + (et*16+c)*72 + wt*16 + q*4) = u;
      }
    }
#pragma unroll
    for (int et=0; et<4; ++et) r2[et]=rsqrtf(qsum(ss[et])*(1.f/64.f)+EPSF);
  }
  // Cholesky head (rows permuted diag-first; diag = rows 0..7 = wt0, q<2)
  float ldet[4];
  {
    f4 a3[3][4];
#pragma unroll
    for (int wt=0; wt<3; ++wt) for (int et=0; et<4; ++et) a3[wt][et]=z4;
    gemmH<3>(ws16+HWT, actL, a3, c, q);
    float ldp[4]={0.f,0.f,0.f,0.f};
#pragma unroll
    for (int wt=0; wt<3; ++wt){
      const f4 hbv = *(const f4*)(wsf + HBPO + wt*16 + q*4);
#pragma unroll
      for (int et=0; et<4; ++et){
        float t0=r2[et]*a3[wt][et][0]+hbv[0], t1=r2[et]*a3[wt][et][1]+hbv[1];
        float t2=r2[et]*a3[wt][et][2]+hbv[2], t3=r2[et]*a3[wt][et][3]+hbv[3];
        if (wt==0 && q<2){
          t0=fmaxf(t0,0.f)+__logf(1.f+__expf(-fabsf(t0)));
          t1=fmaxf(t1,0.f)+__logf(1.f+__expf(-fabsf(t1)));
          t2=fmaxf(t2,0.f)+__logf(1.f+__expf(-fabsf(t2)));
          t3=fmaxf(t3,0.f)+__logf(1.f+__expf(-fabsf(t3)));
          ldp[et] += __logf(t0)+__logf(t1)+__logf(t2)+__logf(t3);
        }
        if (wt<2 || q==0){
          u32x2 u = {pk2(t0,t1), pk2(t2,t3)};
          *(u32x2*)(triL + (et*16+c)*44 + wt*16 + q*4) = u;
        }
      }
    }
#pragma unroll
    for (int et=0; et<4; ++et) ldet[et]=qsum(ldp[et]);
  }

  // =================== critic ===================
#pragma unroll
  for (int wt=0; wt<4; ++wt) for (int et=0; et<4; ++et) acc[wt][et]=z4;
  gemmX<4>(ws16+CW1T, xf, acc, c, q);
  float rc[4];
  {
    float ss[4]={0.f,0.f,0.f,0.f};
#pragma unroll
    for (int wt=0; wt<4; ++wt){
      const f4 bv = *(const f4*)(cb1 + wt*16 + q*4);
      const f4 rw = *(const f4*)(c_rms + wt*16 + q*4);
#pragma unroll
      for (int et=0; et<4; ++et){
        float s0=siluf(acc[wt][et][0]+bv[0]), s1=siluf(acc[wt][et][1]+bv[1]);
        float s2=siluf(acc[wt][et][2]+bv[2]), s3=siluf(acc[wt][et][3]+bv[3]);
        ss[et] += s0*s0+s1*s1+s2*s2+s3*s3;
        u32x2 u = {pk2(s0*rw[0],s1*rw[1]), pk2(s2*rw[2],s3*rw[3])};
        *(u32x2*)(actL + (et*16+c)*72 + wt*16 + q*4) = u;
      }
    }
#pragma unroll
    for (int et=0; et<4; ++et) rc[et]=rsqrtf(qsum(ss[et])*(1.f/64.f)+EPSF);
  }
  float vv[4];
  {
#pragma unroll
    for (int wt=0; wt<4; ++wt) for (int et=0; et<4; ++et) acc[wt][et]=z4;
    gemmH<4>(ws16+CW2T, actL, acc, c, q);
    float vp[4]={0.f,0.f,0.f,0.f};
#pragma unroll
    for (int wt=0; wt<4; ++wt){
      const f4 bv = *(const f4*)(cb2 + wt*16 + q*4);
      const f4 wv = *(const f4*)(cW3 + wt*16 + q*4);
#pragma unroll
      for (int et=0; et<4; ++et){
        vp[et] = fmaf(siluf(rc[et]*acc[wt][et][0]+bv[0]), wv[0], vp[et]);
        vp[et] = fmaf(siluf(rc[et]*acc[wt][et][1]+bv[1]), wv[1], vp[et]);
        vp[et] = fmaf(siluf(rc[et]*acc[wt][et][2]+bv[2]), wv[2], vp[et]);
        vp[et] = fmaf(siluf(rc[et]*acc[wt][et][3]+bv[3]), wv[3], vp[et]);
      }
    }
    const float cb3v = cb3[0];
#pragma unroll
    for (int et=0; et<4; ++et) vv[et]=qsum(vp[et])+cb3v;
  }

  // =================== per-element: nst, action passthrough ===================
  const int l = lane;
  const size_t bb = (size_t)(b0+l)*8;
  float nst[8], fld=0.f;
  {
    f4 a0=*(const f4*)(action+bb), a1=*(const f4*)(action+bb+4);
    f4 zr0=*(const f4*)(z_rpo+bb), zr1=*(const f4*)(z_rpo+bb+4);
    *(f4*)(out+bb)=a0; *(f4*)(out+bb+4)=a1;
#pragma unroll
    for (int j=0;j<4;++j){
      nst[j]   = a0[j]-amL[l*10+j]  -zr0[j];
      nst[4+j] = a1[j]-amL[l*10+4+j]-zr1[j];
    }
#pragma unroll
    for (int j=0;j<8;++j) nstL[l*10+j]=nst[j];
  }

  // =================== flow (hidL aliases actL; stL aliases amL) ===================
#pragma unroll
  for (int ii=0; ii<4; ++ii){
    const int i = 3-ii;
    const int cb = (i&1)?4:0, yb = (i&1)?0:4;
    f4 a2[2][4];
#pragma unroll
    for (int wt=0; wt<2; ++wt) for (int et=0; et<4; ++et) a2[wt][et]=z4;
    gemmX<2>(ws16+FW1XT+i*4096, xf, a2, c, q);
    float nv[4][4];
#pragma unroll
    for (int et=0; et<4; ++et){
      const float* np = nstL + (et*16+c)*10 + cb;
      f2 t0=*(const f2*)np, t1=*(const f2*)(np+2);
      nv[et][0]=t0[0]; nv[et][1]=t0[1]; nv[et][2]=t1[0]; nv[et][3]=t1[1];
    }
#pragma unroll
    for (int wt=0; wt<2; ++wt){
      const f4 bv = *(const f4*)(fb1 + i*32 + wt*16 + q*4);
      float sh[4][4];
#pragma unroll
      for (int r=0; r<4; ++r){
        const f4 wc = *(const f4*)(wsf + W1CTO + i*128 + (wt*16+q*4+r)*4);
#pragma unroll
        for (int et=0; et<4; ++et){
          float hv = a2[wt][et][r] + bv[r]
                   + wc[0]*nv[et][0] + wc[1]*nv[et][1]
                   + wc[2]*nv[et][2] + wc[3]*nv[et][3];
          sh[et][r] = siluf(hv);
        }
      }
#pragma unroll
      for (int et=0; et<4; ++et){
        u32x2 u = {pk2(sh[et][0],sh[et][1]), pk2(sh[et][2],sh[et][3])};
        *(u32x2*)(hidL + (et*16+c)*40 + wt*16 + q*4) = u;
      }
    }
    // second flow layer: st = silu(hid) @ fW2 + fb2
    {
      const v8s wf3 = *(const v8s*)(ws16 + FW2T + i*512 + c*32 + q*8);
      f4 as[4];
#pragma unroll
      for (int et=0; et<4; ++et){
        const v8s hf = *(const v8s*)(hidL + (et*16+c)*40 + q*8);
        f4 a1s = z4;
        a1s = MFMA16(wf3, hf, a1s, 0,0,0);
        as[et]=a1s;
      }
      if (q<2){
        const f4 fbv = *(const f4*)(fb2 + i*8 + q*4);
#pragma unroll
        for (int et=0; et<4; ++et){
          float* p = amL + (et*16+c)*10 + q*4;   // stL
          *(f2*)p     = (f2){as[et][0]+fbv[0], as[et][1]+fbv[1]};
          *(f2*)(p+2) = (f2){as[et][2]+fbv[2], as[et][3]+fbv[3]};
        }
      }
    }
    // per-element update
    {
      float sr0=amL[l*10+0], sr1=amL[l*10+1], sr2=amL[l*10+2], sr3=amL[l*10+3];
      float th0=amL[l*10+4], th1=amL[l*10+5], th2=amL[l*10+6], th3=amL[l*10+7];
      float s0=2.f-4.f/(__expf(2.f*sr0)+1.f);
      float s1=2.f-4.f/(__expf(2.f*sr1)+1.f);
      float s2=2.f-4.f/(__expf(2.f*sr2)+1.f);
      float s3=2.f-4.f/(__expf(2.f*sr3)+1.f);
      nst[yb+0]=(nst[yb+0]-th0)*__expf(-s0);
      nst[yb+1]=(nst[yb+1]-th1)*__expf(-s1);
      nst[yb+2]=(nst[yb+2]-th2)*__expf(-s2);
      nst[yb+3]=(nst[yb+3]-th3)*__expf(-s3);
      nstL[l*10+yb+0]=nst[yb+0]; nstL[l*10+yb+1]=nst[yb+1];
      nstL[l*10+yb+2]=nst[yb+2]; nstL[l*10+yb+3]=nst[yb+3];
      fld += s0+s1+s2+s3;
    }
  }

  // =================== triangular solve + outputs ===================
  {
    constexpr int INVPERM[36] = {0,8,1,9,10,2,11,12,13,3,14,15,16,17,4,18,19,20,
                                 21,22,5,23,24,25,26,27,28,6,29,30,31,32,33,34,35,7};
    float tri[36];
#pragma unroll
    for (int j=0;j<36;++j){
      unsigned h = triL[l*44 + INVPERM[j]];
      tri[j] = ubits(h<<16);
    }
    float zv[8], mahal=0.f;
#pragma unroll
    for (int r=0;r<8;++r){
      float s=nst[r];
      const int base=(r*(r+1))>>1;
#pragma unroll
      for (int cc=0;cc<r;++cc) s -= tri[base+cc]*zv[cc];
      const float z = s/tri[base+r];
      zv[r]=z; mahal+=z*z;
    }
    const float ldet_s = (l<16)?ldet[0]:(l<32)?ldet[1]:(l<48)?ldet[2]:ldet[3];
    const float v_s    = (l<16)?vv[0]:(l<32)?vv[1]:(l<48)?vv[2]:vv[3];
    const float lp = -0.5f*(8.f*LOG2PI+mahal) - ldet_s - fld;
    const float en =  0.5f*(8.f*(1.f+LOG2PI)) + ldet_s + fld;
    out[(size_t)Btot*8  + b0 + l] = lp;
    out[(size_t)Btot*9  + b0 + l] = en;
    out[(size_t)Btot*10 + b0 + l] = v_s;
  }
}

extern "C" void kernel_launch(void* const* d_in, const int* in_sizes, int n_in,
                              void* d_out, int out_size, void* d_ws, size_t ws_size,
                              hipStream_t stream) {
  const float* x      = (const float*)d_in[0];
  const float* action = (const float*)d_in[1];
  const float* z_rpo  = (const float*)d_in[2];
  const float* cW1    = (const float*)d_in[3];
  const float* cb1    = (const float*)d_in[4];
  const float* c_rms  = (const float*)d_in[5];
  const float* cW2    = (const float*)d_in[6];
  const float* cb2    = (const float*)d_in[7];
  const float* cW3    = (const float*)d_in[8];
  const float* cb3    = (const float*)d_in[9];
  const float* aW1    = (const float*)d_in[10];
  const float* ab1    = (const float*)d_in[11];
  const float* aW2    = (const float*)d_in[12];
  const float* ab2    = (const float*)d_in[13];
  const float* mW     = (const float*)d_in[14];
  const float* mb     = (const float*)d_in[15];
  const float* tW1    = (const float*)d_in[16];
  const float* tb1    = (const float*)d_in[17];
  const float* t_rms1 = (const float*)d_in[18];
  const float* tW2    = (const float*)d_in[19];
  const float* tb2    = (const float*)d_in[20];
  const float* t_rms2 = (const float*)d_in[21];
  const float* hW     = (const float*)d_in[22];
  const float* hb     = (const float*)d_in[23];
  const float* fW1    = (const float*)d_in[24];
  const float* fb1    = (const float*)d_in[25];
  const float* fW2    = (const float*)d_in[26];
  const float* fb2    = (const float*)d_in[27];
  float* out = (float*)d_out;

  unsigned short* ws16 = (unsigned short*)d_ws;
  float* wsf = (float*)((char*)d_ws + WS_BF16_TOTAL*2);

  const int Btot = in_sizes[0] / 128;   // 131072

  hipLaunchKernelGGL(prep_kernel, dim3(64), dim3(256), 0, stream,
                     aW1, aW2, mW, tW1, tW2, hW, hb, cW1, cW2, fW1, fW2, ws16, wsf);
  hipLaunchKernelGGL(policy_kernel, dim3(Btot/64), dim3(64), 0, stream,
                     x, action, z_rpo, cb1, c_rms, cb2, cW3, cb3,
                     ab1, ab2, mb, tb1, t_rms1, tb2, t_rms2, fb1, fb2,
                     ws16, wsf, out, Btot);
}